// Round 6
// baseline (184.742 us; speedup 1.0000x reference)
//
#include <hip/hip_runtime.h>

typedef __attribute__((ext_vector_type(4))) float f32x4;
typedef __attribute__((ext_vector_type(16))) float f32x16;
typedef __attribute__((ext_vector_type(8))) short short8;

#define DEV static __device__ __forceinline__

DEV unsigned short f2bf(float f) {
  union { float f; unsigned u; } x; x.f = f;
  unsigned r = x.u + 0x7fffu + ((x.u >> 16) & 1u);
  return (unsigned short)(r >> 16);
}

DEV float bf2f(unsigned short u) {
  union { unsigned u; float f; } x; x.u = ((unsigned)u) << 16;
  return x.f;
}

DEV f32x4 mfma16(short8 a, short8 b, f32x4 c) {
  return __builtin_amdgcn_mfma_f32_16x16x32_bf16(a, b, c, 0, 0, 0);
}

DEV f32x16 mfma32(short8 a, short8 b, f32x16 c) {
  return __builtin_amdgcn_mfma_f32_32x32x16_bf16(a, b, c, 0, 0, 0);
}

DEV void gload16(const void* g, void* l) {
  __builtin_amdgcn_global_load_lds(
      (const __attribute__((address_space(1))) void*)g,
      (__attribute__((address_space(3))) void*)l, 16, 0, 0);
}

DEV float exp2f_fast(float x) {
  float r;
  asm("v_exp_f32 %0, %1" : "=v"(r) : "v"(x));
  return r;
}

DEV unsigned cvtpk(float lo, float hi) {
  unsigned r;
  asm("v_cvt_pk_bf16_f32 %0, %1, %2" : "=v"(r) : "v"(lo), "v"(hi));
  return r;
}

DEV short8 mk8(unsigned w0, unsigned w1, unsigned w2, unsigned w3) {
  union { unsigned u[4]; short8 s; } x;
  x.u[0] = w0; x.u[1] = w1; x.u[2] = w2; x.u[3] = w3;
  return x.s;
}

// ---------------- fp32 -> bf16 elementwise ----------------
__global__ __launch_bounds__(256) void k_convert(const float* __restrict__ in,
                                                 unsigned short* __restrict__ out) {
  size_t i = (size_t)blockIdx.x * 256 + threadIdx.x;
  const f32x4* p = (const f32x4*)(in + i * 8);
  f32x4 a = p[0], b = p[1];
  short8 r;
  r[0] = f2bf(a[0]); r[1] = f2bf(a[1]); r[2] = f2bf(a[2]); r[3] = f2bf(a[3]);
  r[4] = f2bf(b[0]); r[5] = f2bf(b[1]); r[6] = f2bf(b[2]); r[7] = f2bf(b[3]);
  *(short8*)(out + i * 8) = r;
}

// ---------------- fp32 [R][C] -> bf16 [C][R] (weights) ----------------
__global__ __launch_bounds__(256) void k_transpose_f32_bf16(
    const float* __restrict__ in, unsigned short* __restrict__ out, int R, int C) {
  __shared__ unsigned short T[64 * 72];
  int r0 = blockIdx.y * 64, c0 = blockIdx.x * 64;
  int t = threadIdx.x;
  int rr = t >> 2, seg = t & 3;
  const float* p = in + (size_t)(r0 + rr) * C + c0 + seg * 16;
#pragma unroll
  for (int q = 0; q < 4; ++q) {
    f32x4 v = *(const f32x4*)(p + q * 4);
#pragma unroll
    for (int e = 0; e < 4; ++e) T[rr * 72 + seg * 16 + q * 4 + e] = f2bf(v[e]);
  }
  __syncthreads();
  short8 o0, o1;
#pragma unroll
  for (int e = 0; e < 8; ++e) o0[e] = (short)T[(seg * 16 + e) * 72 + rr];
#pragma unroll
  for (int e = 0; e < 8; ++e) o1[e] = (short)T[(seg * 16 + 8 + e) * 72 + rr];
  unsigned short* q2 = out + (size_t)(c0 + rr) * R + r0 + seg * 16;
  *(short8*)q2 = o0;
  *(short8*)(q2 + 8) = o1;
}

// ---------------- build V^T [B*H][64][2048] from qkv ----------------
__global__ __launch_bounds__(256) void k_build_vt(const unsigned short* __restrict__ qkv,
                                                  unsigned short* __restrict__ vt) {
  __shared__ unsigned short T[64 * 72];
  int n0 = blockIdx.x * 64;
  int bh = blockIdx.y;
  int b = bh >> 3, h = bh & 7;
  int t = threadIdx.x;
  int rr = t >> 2, seg = t & 3;
  const unsigned short* p =
      qkv + (size_t)(b * 2048 + n0 + rr) * 1536 + 1024 + h * 64 + seg * 16;
  *(short8*)&T[rr * 72 + seg * 16] = *(const short8*)p;
  *(short8*)&T[rr * 72 + seg * 16 + 8] = *(const short8*)(p + 8);
  __syncthreads();
  short8 o0, o1;
#pragma unroll
  for (int e = 0; e < 8; ++e) o0[e] = (short)T[(seg * 16 + e) * 72 + rr];
#pragma unroll
  for (int e = 0; e < 8; ++e) o1[e] = (short)T[(seg * 16 + 8 + e) * 72 + rr];
  unsigned short* q2 = vt + (size_t)(bh * 64 + rr) * 2048 + n0 + seg * 16;
  *(short8*)q2 = o0;
  *(short8*)(q2 + 8) = o1;
}

// ---------------- GEMM: C[M][N] = A[M][K] * Bt[N][K]^T (+bias) ----------------
template <bool F32OUT>
__global__ __launch_bounds__(256) void k_gemm_bt(
    const unsigned short* __restrict__ A, const unsigned short* __restrict__ Bt,
    void* __restrict__ Cp, const float* __restrict__ bias, int M, int N, int K) {
  __shared__ unsigned short Asm[128 * 64];
  __shared__ unsigned short Bsm[128 * 64];
  const int tid = threadIdx.x;
  const int lane = tid & 63, w = tid >> 6;
  const int wr = w >> 1, wc = w & 1;
  const int bm = blockIdx.y * 128, bn = blockIdx.x * 128;
  const int l15 = lane & 15, l4 = lane >> 4;
  f32x4 acc[4][4] = {};
  for (int k0 = 0; k0 < K; k0 += 64) {
    __syncthreads();
#pragma unroll
    for (int j = 0; j < 4; ++j) {
      int c = j * 256 + tid;
      gload16(A + (size_t)(bm + (c >> 3)) * K + k0 + ((c & 7) << 3),
              Asm + (size_t)(j * 256 + w * 64) * 8);
    }
#pragma unroll
    for (int j = 0; j < 4; ++j) {
      int c = j * 256 + tid;
      gload16(Bt + (size_t)(bn + (c >> 3)) * K + k0 + ((c & 7) << 3),
              Bsm + (size_t)(j * 256 + w * 64) * 8);
    }
    __syncthreads();
#pragma unroll
    for (int kc = 0; kc < 2; ++kc) {
      short8 av[4], bv[4];
#pragma unroll
      for (int i = 0; i < 4; ++i)
        av[i] = *(const short8*)&Asm[(wr * 64 + i * 16 + l15) * 64 + kc * 32 + l4 * 8];
#pragma unroll
      for (int j = 0; j < 4; ++j)
        bv[j] = *(const short8*)&Bsm[(wc * 64 + j * 16 + l15) * 64 + kc * 32 + l4 * 8];
#pragma unroll
      for (int i = 0; i < 4; ++i)
#pragma unroll
        for (int j = 0; j < 4; ++j)
          acc[i][j] = mfma16(av[i], bv[j], acc[i][j]);
    }
  }
#pragma unroll
  for (int i = 0; i < 4; ++i) {
#pragma unroll
    for (int j = 0; j < 4; ++j) {
      int col = bn + wc * 64 + j * 16 + l15;
      float bb = 0.f;
      if constexpr (F32OUT) bb = bias[col];
#pragma unroll
      for (int v = 0; v < 4; ++v) {
        int row = bm + wr * 64 + i * 16 + l4 * 4 + v;
        if constexpr (F32OUT) {
          ((float*)Cp)[(size_t)row * N + col] = acc[i][j][v] + bb;
        } else {
          ((unsigned short*)Cp)[(size_t)row * N + col] = f2bf(acc[i][j][v]);
        }
      }
    }
  }
}

// ---------------- flash attention, 2-deep pipelined ----------------
// grid (N/128, B*H), 256 threads = 4 waves, each wave owns 32 q-rows.
// Iter t: prefetch(t+2) -> QK^T(t+1) MFMA -> softmax(t) VALU -> PV(t) MFMA
//         -> LDS-write staged(t+2) -> barrier.
// K double-buffered, V triple-buffered (V(t+2) write vs V(t) read isolation).
__global__ __launch_bounds__(256, 2) void k_attn3(const unsigned short* __restrict__ qkv,
                                                  const unsigned short* __restrict__ vtg,
                                                  unsigned short* __restrict__ O) {
  __shared__ unsigned short Ks[2][4096];
  __shared__ unsigned short Vs[3][4096];
  const int tid = threadIdx.x;
  const int lane = tid & 63, w = tid >> 6;
  const int l31 = lane & 31, hi = lane >> 5;
  const int bh = blockIdx.y, b = bh >> 3, h = bh & 7;
  const int q0 = blockIdx.x * 128 + w * 32;
  const float CL = 0.044194173824159216f * 1.4426950408889634f;  // SCALE*log2(e)

  // Q load, fold SCALE*log2e into bf16 Q
  short8 qf[4];
  {
    const unsigned short* qp = qkv + (size_t)(b * 2048 + q0 + l31) * 1536 + h * 64;
#pragma unroll
    for (int ks = 0; ks < 4; ++ks) {
      short8 raw = *(const short8*)(qp + ks * 16 + hi * 8);
      short8 f;
#pragma unroll
      for (int e = 0; e < 8; ++e)
        f[e] = (short)f2bf(bf2f((unsigned short)raw[e]) * CL);
      qf[ks] = f;
    }
  }

  // staging geometry: thread -> rows (sr, sr+32), 16B segment seg
  const int sr = tid >> 3, seg = tid & 7;
  const unsigned short* kg = qkv + (size_t)b * 2048 * 1536 + 512 + h * 64 + seg * 8;
  const unsigned short* vg = vtg + (size_t)bh * 64 * 2048 + seg * 8;
  const int so0 = sr * 64 + ((seg * 8) ^ ((sr & 7) << 3));
  const int so1 = so0 + 32 * 64;  // (sr+32)&7 == sr&7

  // prologue: stage tiles 0 and 1
  {
    short8 k0a = *(const short8*)(kg + (size_t)sr * 1536);
    short8 k0b = *(const short8*)(kg + (size_t)(sr + 32) * 1536);
    short8 v0a = *(const short8*)(vg + (size_t)sr * 2048);
    short8 v0b = *(const short8*)(vg + (size_t)(sr + 32) * 2048);
    short8 k1a = *(const short8*)(kg + (size_t)(64 + sr) * 1536);
    short8 k1b = *(const short8*)(kg + (size_t)(64 + sr + 32) * 1536);
    short8 v1a = *(const short8*)(vg + (size_t)sr * 2048 + 64);
    short8 v1b = *(const short8*)(vg + (size_t)(sr + 32) * 2048 + 64);
    *(short8*)&Ks[0][so0] = k0a; *(short8*)&Ks[0][so1] = k0b;
    *(short8*)&Vs[0][so0] = v0a; *(short8*)&Vs[0][so1] = v0b;
    *(short8*)&Ks[1][so0] = k1a; *(short8*)&Ks[1][so1] = k1b;
    *(short8*)&Vs[1][so0] = v1a; *(short8*)&Vs[1][so1] = v1b;
  }
  __syncthreads();

  const int rsw = (l31 & 7) << 3;  // read swizzle (shorts)

  // QK^T(0)
  f32x16 st0 = {}, st1 = {};
  {
    const unsigned short* kb = Ks[0];
    __builtin_amdgcn_s_setprio(1);
#pragma unroll
    for (int ks = 0; ks < 4; ++ks) {
      int col = ks * 16 + hi * 8;
      short8 kf0 = *(const short8*)&kb[l31 * 64 + (col ^ rsw)];
      short8 kf1 = *(const short8*)&kb[(32 + l31) * 64 + (col ^ rsw)];
      st0 = mfma32(kf0, qf[ks], st0);
      st1 = mfma32(kf1, qf[ks], st1);
    }
    __builtin_amdgcn_s_setprio(0);
  }
  __syncthreads();  // protect Ks[0] from iter-0's K(2) staging write

  unsigned short* kread = Ks[1];   // holds K(t+1)
  unsigned short* kwrite = Ks[0];  // destination for K(t+2)
  unsigned short* vcur = Vs[0];    // V(t)
  unsigned short* vnxt = Vs[1];    // V(t+1)
  unsigned short* vstg = Vs[2];    // destination for V(t+2)

  f32x16 oacc0 = {}, oacc1 = {};
  float m_run = 0.f, l_run = 0.f;

  for (int t = 0; t < 32; ++t) {
    // global prefetch for tile t+2
    short8 pk0, pk1, pv0, pv1;
    const bool has2 = (t < 30);
    if (has2) {
      int kv = (t + 2) * 64;
      pk0 = *(const short8*)(kg + (size_t)(kv + sr) * 1536);
      pk1 = *(const short8*)(kg + (size_t)(kv + sr + 32) * 1536);
      pv0 = *(const short8*)(vg + (size_t)sr * 2048 + kv);
      pv1 = *(const short8*)(vg + (size_t)(sr + 32) * 2048 + kv);
    }

    // QK^T(t+1) from kread — independent MFMA work to overlap softmax(t)
    f32x16 ns0 = {}, ns1 = {};
    if (t < 31) {
      __builtin_amdgcn_s_setprio(1);
#pragma unroll
      for (int ks = 0; ks < 4; ++ks) {
        int col = ks * 16 + hi * 8;
        short8 kf0 = *(const short8*)&kread[l31 * 64 + (col ^ rsw)];
        short8 kf1 = *(const short8*)&kread[(32 + l31) * 64 + (col ^ rsw)];
        ns0 = mfma32(kf0, qf[ks], ns0);
        ns1 = mfma32(kf1, qf[ks], ns1);
      }
      __builtin_amdgcn_s_setprio(0);
    }

    // ---- softmax(t) on st0/st1 ----
    float tm[8];
#pragma unroll
    for (int r = 0; r < 8; ++r)
      tm[r] = fmaxf(fmaxf(st0[r], st0[r + 8]), fmaxf(st1[r], st1[r + 8]));
    float pm = fmaxf(fmaxf(fmaxf(tm[0], tm[1]), fmaxf(tm[2], tm[3])),
                     fmaxf(fmaxf(tm[4], tm[5]), fmaxf(tm[6], tm[7])));
    pm = fmaxf(pm, __shfl_xor(pm, 32));

    if (!__all(pm <= m_run + 11.5f)) {  // defer-max (rare)
      float mn = fmaxf(m_run, pm);
      float al = exp2f_fast(m_run - mn);
#pragma unroll
      for (int r = 0; r < 16; ++r) {
        int qd = (r & 3) + 8 * (r >> 2) + 4 * hi;
        float a = __shfl(al, qd);
        oacc0[r] *= a;
        oacc1[r] *= a;
      }
      l_run *= al;
      m_run = mn;
    }

    float lsum = 0.f;
    short8 pa[4];
#pragma unroll
    for (int s = 0; s < 2; ++s) {
      const f32x16& stv = s ? st1 : st0;
      float p[16];
      float la = 0.f, lb = 0.f;
#pragma unroll
      for (int r = 0; r < 8; ++r) { p[r] = exp2f_fast(stv[r] - m_run); la += p[r]; }
#pragma unroll
      for (int r = 8; r < 16; ++r) { p[r] = exp2f_fast(stv[r] - m_run); lb += p[r]; }
      lsum += la + lb;
#pragma unroll
      for (int g = 0; g < 2; ++g) {
        unsigned pkA0 = cvtpk(p[8 * g + 0], p[8 * g + 1]);
        unsigned pkA1 = cvtpk(p[8 * g + 2], p[8 * g + 3]);
        unsigned pkB0 = cvtpk(p[8 * g + 4], p[8 * g + 5]);
        unsigned pkB1 = cvtpk(p[8 * g + 6], p[8 * g + 7]);
        unsigned tA0 = __shfl_xor(pkA0, 32), tA1 = __shfl_xor(pkA1, 32);
        unsigned tB0 = __shfl_xor(pkB0, 32), tB1 = __shfl_xor(pkB1, 32);
        unsigned w0 = hi ? tB0 : pkA0;
        unsigned w1 = hi ? tB1 : pkA1;
        unsigned w2 = hi ? pkB0 : tA0;
        unsigned w3 = hi ? pkB1 : tA1;
        pa[2 * s + g] = mk8(w0, w1, w2, w3);
      }
    }
    lsum += __shfl_xor(lsum, 32);
    l_run += lsum;

    // ---- PV(t) from vcur ----
    __builtin_amdgcn_s_setprio(1);
#pragma unroll
    for (int ks = 0; ks < 4; ++ks) {
      int col = ks * 16 + hi * 8;
      short8 vf0 = *(const short8*)&vcur[l31 * 64 + (col ^ rsw)];
      short8 vf1 = *(const short8*)&vcur[(32 + l31) * 64 + (col ^ rsw)];
      oacc0 = mfma32(pa[ks], vf0, oacc0);
      oacc1 = mfma32(pa[ks], vf1, oacc1);
    }
    __builtin_amdgcn_s_setprio(0);

    // stage tile t+2 into buffers no one reads this iter
    if (has2) {
      *(short8*)&kwrite[so0] = pk0; *(short8*)&kwrite[so1] = pk1;
      *(short8*)&vstg[so0] = pv0;   *(short8*)&vstg[so1] = pv1;
    }
    __syncthreads();

    st0 = ns0; st1 = ns1;
    { unsigned short* tp = kread; kread = kwrite; kwrite = tp; }
    { unsigned short* tp = vcur; vcur = vnxt; vnxt = vstg; vstg = tp; }
  }

  // epilogue: divide by l (shfl broadcast), write bf16 O
#pragma unroll
  for (int r = 0; r < 16; ++r) {
    int qd = (r & 3) + 8 * (r >> 2) + 4 * hi;
    float linv = 1.0f / __shfl(l_run, qd);
    size_t row = (size_t)(b * 2048 + q0 + qd) * 512 + h * 64;
    O[row + l31] = f2bf(oacc0[r] * linv);
    O[row + 32 + l31] = f2bf(oacc1[r] * linv);
  }
}

extern "C" void kernel_launch(void* const* d_in, const int* in_sizes, int n_in,
                              void* d_out, int out_size, void* d_ws, size_t ws_size,
                              hipStream_t stream) {
  const float* x = (const float*)d_in[0];
  const float* w_qkv = (const float*)d_in[1];
  const float* w_out = (const float*)d_in[2];
  const float* b_out = (const float*)d_in[3];
  float* out = (float*)d_out;
  char* ws = (char*)d_ws;

  unsigned short* xb    = (unsigned short*)(ws + 0);         //  8 MB [8192][512]
  unsigned short* wqkvT = (unsigned short*)(ws + 8388608);   //  1.5 MB [1536][512]
  unsigned short* woutT = (unsigned short*)(ws + 9961472);   //  0.5 MB [512][512]
  unsigned short* qkvb  = (unsigned short*)(ws + 10485760);  // 24 MB [8192][1536]
  unsigned short* vtb   = (unsigned short*)(ws + 35651584);  //  8 MB [32][64][2048]
  unsigned short* Ob    = (unsigned short*)(ws + 44040192);  //  8 MB [8192][512]

  k_convert<<<2048, 256, 0, stream>>>(x, xb);
  k_transpose_f32_bf16<<<dim3(24, 8), 256, 0, stream>>>(w_qkv, wqkvT, 512, 1536);
  k_transpose_f32_bf16<<<dim3(8, 8), 256, 0, stream>>>(w_out, woutT, 512, 512);
  k_gemm_bt<false><<<dim3(12, 64), 256, 0, stream>>>(xb, wqkvT, (void*)qkvb, nullptr,
                                                     8192, 1536, 512);
  k_build_vt<<<dim3(32, 32), 256, 0, stream>>>(qkvb, vtb);
  k_attn3<<<dim3(16, 32), 256, 0, stream>>>(qkvb, vtb, Ob);
  k_gemm_bt<true><<<dim3(4, 64), 256, 0, stream>>>(Ob, woutT, (void*)out, b_out,
                                                   8192, 512, 512);
}

// Round 9
// 181.962 us; speedup vs baseline: 1.0153x; 1.0153x over previous
//
#include <hip/hip_runtime.h>

typedef __attribute__((ext_vector_type(4))) float f32x4;
typedef __attribute__((ext_vector_type(16))) float f32x16;
typedef __attribute__((ext_vector_type(8))) short short8;

#define DEV static __device__ __forceinline__

DEV unsigned short f2bf(float f) {
  union { float f; unsigned u; } x; x.f = f;
  unsigned r = x.u + 0x7fffu + ((x.u >> 16) & 1u);
  return (unsigned short)(r >> 16);
}

DEV float bf2f(unsigned short u) {
  union { unsigned u; float f; } x; x.u = ((unsigned)u) << 16;
  return x.f;
}

DEV f32x4 mfma16(short8 a, short8 b, f32x4 c) {
  return __builtin_amdgcn_mfma_f32_16x16x32_bf16(a, b, c, 0, 0, 0);
}

DEV f32x16 mfma32(short8 a, short8 b, f32x16 c) {
  return __builtin_amdgcn_mfma_f32_32x32x16_bf16(a, b, c, 0, 0, 0);
}

DEV void gload16(const void* g, void* l) {
  __builtin_amdgcn_global_load_lds(
      (const __attribute__((address_space(1))) void*)g,
      (__attribute__((address_space(3))) void*)l, 16, 0, 0);
}

DEV float exp2f_fast(float x) {
  float r;
  asm("v_exp_f32 %0, %1" : "=v"(r) : "v"(x));
  return r;
}

DEV unsigned cvtpk(float lo, float hi) {
  unsigned r;
  asm("v_cvt_pk_bf16_f32 %0, %1, %2" : "=v"(r) : "v"(lo), "v"(hi));
  return r;
}

DEV short8 mk8(unsigned w0, unsigned w1, unsigned w2, unsigned w3) {
  union { unsigned u[4]; short8 s; } x;
  x.u[0] = w0; x.u[1] = w1; x.u[2] = w2; x.u[3] = w3;
  return x.s;
}

// ---------------- fp32 -> bf16 elementwise ----------------
__global__ __launch_bounds__(256) void k_convert(const float* __restrict__ in,
                                                 unsigned short* __restrict__ out) {
  size_t i = (size_t)blockIdx.x * 256 + threadIdx.x;
  const f32x4* p = (const f32x4*)(in + i * 8);
  f32x4 a = p[0], b = p[1];
  short8 r;
  r[0] = f2bf(a[0]); r[1] = f2bf(a[1]); r[2] = f2bf(a[2]); r[3] = f2bf(a[3]);
  r[4] = f2bf(b[0]); r[5] = f2bf(b[1]); r[6] = f2bf(b[2]); r[7] = f2bf(b[3]);
  *(short8*)(out + i * 8) = r;
}

// ---------------- fp32 [R][C] -> bf16 [C][R] (weights) ----------------
__global__ __launch_bounds__(256) void k_transpose_f32_bf16(
    const float* __restrict__ in, unsigned short* __restrict__ out, int R, int C) {
  __shared__ unsigned short T[64 * 72];
  int r0 = blockIdx.y * 64, c0 = blockIdx.x * 64;
  int t = threadIdx.x;
  int rr = t >> 2, seg = t & 3;
  const float* p = in + (size_t)(r0 + rr) * C + c0 + seg * 16;
#pragma unroll
  for (int q = 0; q < 4; ++q) {
    f32x4 v = *(const f32x4*)(p + q * 4);
#pragma unroll
    for (int e = 0; e < 4; ++e) T[rr * 72 + seg * 16 + q * 4 + e] = f2bf(v[e]);
  }
  __syncthreads();
  short8 o0, o1;
#pragma unroll
  for (int e = 0; e < 8; ++e) o0[e] = (short)T[(seg * 16 + e) * 72 + rr];
#pragma unroll
  for (int e = 0; e < 8; ++e) o1[e] = (short)T[(seg * 16 + 8 + e) * 72 + rr];
  unsigned short* q2 = out + (size_t)(c0 + rr) * R + r0 + seg * 16;
  *(short8*)q2 = o0;
  *(short8*)(q2 + 8) = o1;
}

// ---------------- build V^T [B*H][64][2048] from qkv ----------------
__global__ __launch_bounds__(256) void k_build_vt(const unsigned short* __restrict__ qkv,
                                                  unsigned short* __restrict__ vt) {
  __shared__ unsigned short T[64 * 72];
  int n0 = blockIdx.x * 64;
  int bh = blockIdx.y;
  int b = bh >> 3, h = bh & 7;
  int t = threadIdx.x;
  int rr = t >> 2, seg = t & 3;
  const unsigned short* p =
      qkv + (size_t)(b * 2048 + n0 + rr) * 1536 + 1024 + h * 64 + seg * 16;
  *(short8*)&T[rr * 72 + seg * 16] = *(const short8*)p;
  *(short8*)&T[rr * 72 + seg * 16 + 8] = *(const short8*)(p + 8);
  __syncthreads();
  short8 o0, o1;
#pragma unroll
  for (int e = 0; e < 8; ++e) o0[e] = (short)T[(seg * 16 + e) * 72 + rr];
#pragma unroll
  for (int e = 0; e < 8; ++e) o1[e] = (short)T[(seg * 16 + 8 + e) * 72 + rr];
  unsigned short* q2 = vt + (size_t)(bh * 64 + rr) * 2048 + n0 + seg * 16;
  *(short8*)q2 = o0;
  *(short8*)(q2 + 8) = o1;
}

// ---------------- GEMM: C[M][N] = A[M][K] * Bt[N][K]^T (+bias) ----------------
template <bool F32OUT>
__global__ __launch_bounds__(256) void k_gemm_bt(
    const unsigned short* __restrict__ A, const unsigned short* __restrict__ Bt,
    void* __restrict__ Cp, const float* __restrict__ bias, int M, int N, int K) {
  __shared__ unsigned short Asm[128 * 64];
  __shared__ unsigned short Bsm[128 * 64];
  const int tid = threadIdx.x;
  const int lane = tid & 63, w = tid >> 6;
  const int wr = w >> 1, wc = w & 1;
  const int bm = blockIdx.y * 128, bn = blockIdx.x * 128;
  const int l15 = lane & 15, l4 = lane >> 4;
  f32x4 acc[4][4] = {};
  for (int k0 = 0; k0 < K; k0 += 64) {
    __syncthreads();
#pragma unroll
    for (int j = 0; j < 4; ++j) {
      int c = j * 256 + tid;
      gload16(A + (size_t)(bm + (c >> 3)) * K + k0 + ((c & 7) << 3),
              Asm + (size_t)(j * 256 + w * 64) * 8);
    }
#pragma unroll
    for (int j = 0; j < 4; ++j) {
      int c = j * 256 + tid;
      gload16(Bt + (size_t)(bn + (c >> 3)) * K + k0 + ((c & 7) << 3),
              Bsm + (size_t)(j * 256 + w * 64) * 8);
    }
    __syncthreads();
#pragma unroll
    for (int kc = 0; kc < 2; ++kc) {
      short8 av[4], bv[4];
#pragma unroll
      for (int i = 0; i < 4; ++i)
        av[i] = *(const short8*)&Asm[(wr * 64 + i * 16 + l15) * 64 + kc * 32 + l4 * 8];
#pragma unroll
      for (int j = 0; j < 4; ++j)
        bv[j] = *(const short8*)&Bsm[(wc * 64 + j * 16 + l15) * 64 + kc * 32 + l4 * 8];
#pragma unroll
      for (int i = 0; i < 4; ++i)
#pragma unroll
        for (int j = 0; j < 4; ++j)
          acc[i][j] = mfma16(av[i], bv[j], acc[i][j]);
    }
  }
#pragma unroll
  for (int i = 0; i < 4; ++i) {
#pragma unroll
    for (int j = 0; j < 4; ++j) {
      int col = bn + wc * 64 + j * 16 + l15;
      float bb = 0.f;
      if constexpr (F32OUT) bb = bias[col];
#pragma unroll
      for (int v = 0; v < 4; ++v) {
        int row = bm + wr * 64 + i * 16 + l4 * 4 + v;
        if constexpr (F32OUT) {
          ((float*)Cp)[(size_t)row * N + col] = acc[i][j][v] + bb;
        } else {
          ((unsigned short*)Cp)[(size_t)row * N + col] = f2bf(acc[i][j][v]);
        }
      }
    }
  }
}

// ---------------- flash attention, KV-half-split, 8 waves ----------------
// grid (N/128, B*H), 512 threads. Wave w: qgroup = w&3 (32 q-rows), half = w>>2
// (kv rows half*32..+32 of each 64-tile). Round-2 loop body (bench-verified
// layouts), per-wave work halved, waves/SIMD doubled (2 -> 4). Pair partials
// (m,l,O) combined via LDS epilogue aliasing the dead K/V buffers.
__global__ __launch_bounds__(512, 4) void k_attn4(const unsigned short* __restrict__ qkv,
                                                  const unsigned short* __restrict__ vtg,
                                                  unsigned short* __restrict__ O) {
  __shared__ unsigned short smem[16896];  // 33 KB: Ks[2][4096] | Vs[2][4096] | +1KB ml
  unsigned short* Ks0 = smem;
  unsigned short* Ks1 = smem + 4096;
  unsigned short* Vs0 = smem + 8192;
  unsigned short* Vs1 = smem + 12288;
  const int tid = threadIdx.x;
  const int lane = tid & 63, w = tid >> 6;
  const int qg = w & 3, half = w >> 2;
  const int l31 = lane & 31, hi = lane >> 5;
  const int bh = blockIdx.y, b = bh >> 3, h = bh & 7;
  const int q0 = blockIdx.x * 128 + qg * 32;
  const float CL = 0.044194173824159216f * 1.4426950408889634f;  // SCALE*log2(e)

  // Q load, fold SCALE*log2e into bf16 Q
  short8 qf[4];
  {
    const unsigned short* qp = qkv + (size_t)(b * 2048 + q0 + l31) * 1536 + h * 64;
#pragma unroll
    for (int ks = 0; ks < 4; ++ks) {
      short8 raw = *(const short8*)(qp + ks * 16 + hi * 8);
      short8 f;
#pragma unroll
      for (int e = 0; e < 8; ++e)
        f[e] = (short)f2bf(bf2f((unsigned short)raw[e]) * CL);
      qf[ks] = f;
    }
  }

  // staging: 512 threads cover 64 rows x 64 cols (16B each) for K and V
  const int sr = tid >> 3, seg = tid & 7;
  const unsigned short* kg = qkv + (size_t)b * 2048 * 1536 + 512 + h * 64 + seg * 8;
  const unsigned short* vg = vtg + (size_t)bh * 64 * 2048 + seg * 8;
  const int so = sr * 64 + ((seg * 8) ^ ((sr & 7) << 3));

  // prologue: stage tile 0
  *(short8*)&Ks0[so] = *(const short8*)(kg + (size_t)sr * 1536);
  *(short8*)&Vs0[so] = *(const short8*)(vg + (size_t)sr * 2048);
  __syncthreads();

  const int rsw = (l31 & 7) << 3;          // read swizzle (shorts)
  const int krow = (half * 32 + l31) * 64; // this wave's K rows

  f32x16 oacc0 = {}, oacc1 = {};
  float m_run = 0.f, l_run = 0.f;
  unsigned short* kcur = Ks0; unsigned short* knxt = Ks1;
  unsigned short* vcur = Vs0; unsigned short* vnxt = Vs1;

  for (int t = 0; t < 32; ++t) {
    // reg-prefetch tile t+1 (T14)
    short8 pk, pv;
    if (t < 31) {
      int kv = (t + 1) * 64;
      pk = *(const short8*)(kg + (size_t)(kv + sr) * 1536);
      pv = *(const short8*)(vg + (size_t)sr * 2048 + kv);
    }

    // S^T = K * Q^T over this wave's 32 kv rows (K=64 in 4 steps)
    f32x16 st = {};
    __builtin_amdgcn_s_setprio(1);
#pragma unroll
    for (int ks = 0; ks < 4; ++ks) {
      int col = ks * 16 + hi * 8;
      short8 kf = *(const short8*)&kcur[krow + (col ^ rsw)];
      st = mfma32(kf, qf[ks], st);
    }
    __builtin_amdgcn_s_setprio(0);

    // ---- online softmax (lane-local rows, q = l31) ----
    float tm[8];
#pragma unroll
    for (int r = 0; r < 8; ++r) tm[r] = fmaxf(st[r], st[r + 8]);
    float pm = fmaxf(fmaxf(fmaxf(tm[0], tm[1]), fmaxf(tm[2], tm[3])),
                     fmaxf(fmaxf(tm[4], tm[5]), fmaxf(tm[6], tm[7])));
    pm = fmaxf(pm, __shfl_xor(pm, 32));

    if (!__all(pm <= m_run + 11.5f)) {  // defer-max (rare)
      float mn = fmaxf(m_run, pm);
      float al = exp2f_fast(m_run - mn);
#pragma unroll
      for (int r = 0; r < 16; ++r) {
        int qd = (r & 3) + 8 * (r >> 2) + 4 * hi;
        float a = __shfl(al, qd);
        oacc0[r] *= a;
        oacc1[r] *= a;
      }
      l_run *= al;
      m_run = mn;
    }

    float p[16];
    float la = 0.f, lb = 0.f;
#pragma unroll
    for (int r = 0; r < 8; ++r) { p[r] = exp2f_fast(st[r] - m_run); la += p[r]; }
#pragma unroll
    for (int r = 8; r < 16; ++r) { p[r] = exp2f_fast(st[r] - m_run); lb += p[r]; }
    float lsum = la + lb;
    short8 pa[2];
#pragma unroll
    for (int g = 0; g < 2; ++g) {
      unsigned pkA0 = cvtpk(p[8 * g + 0], p[8 * g + 1]);
      unsigned pkA1 = cvtpk(p[8 * g + 2], p[8 * g + 3]);
      unsigned pkB0 = cvtpk(p[8 * g + 4], p[8 * g + 5]);
      unsigned pkB1 = cvtpk(p[8 * g + 6], p[8 * g + 7]);
      unsigned tA0 = __shfl_xor(pkA0, 32), tA1 = __shfl_xor(pkA1, 32);
      unsigned tB0 = __shfl_xor(pkB0, 32), tB1 = __shfl_xor(pkB1, 32);
      unsigned w0 = hi ? tB0 : pkA0;
      unsigned w1 = hi ? tB1 : pkA1;
      unsigned w2 = hi ? pkB0 : tA0;
      unsigned w3 = hi ? pkB1 : tA1;
      pa[g] = mk8(w0, w1, w2, w3);
    }
    lsum += __shfl_xor(lsum, 32);
    l_run += lsum;

    // ---- O += P V over this wave's kv half ----
    __builtin_amdgcn_s_setprio(1);
#pragma unroll
    for (int ks = 0; ks < 2; ++ks) {
      int col = (half * 2 + ks) * 16 + hi * 8;
      short8 vf0 = *(const short8*)&vcur[l31 * 64 + (col ^ rsw)];
      short8 vf1 = *(const short8*)&vcur[(32 + l31) * 64 + (col ^ rsw)];
      oacc0 = mfma32(pa[ks], vf0, oacc0);
      oacc1 = mfma32(pa[ks], vf1, oacc1);
    }
    __builtin_amdgcn_s_setprio(0);

    // write prefetched tile into the other buffer, single barrier per tile
    if (t < 31) {
      *(short8*)&knxt[so] = pk;
      *(short8*)&vnxt[so] = pv;
    }
    __syncthreads();
    { unsigned short* tp = kcur; kcur = knxt; knxt = tp; }
    { unsigned short* tp = vcur; vcur = vnxt; vnxt = tp; }
  }

  // ---- pair combine: half 1 publishes partials, half 0 merges + writes ----
  float* Opart = (float*)smem;            // [4][32][64] fp32, aliases dead Ks/Vs
  float* mlbuf = (float*)(smem + 16384);  // [4][64]: m then l per q
  if (half == 1) {
    float* op = Opart + qg * 2048;
#pragma unroll
    for (int r = 0; r < 16; ++r) {
      int qd = (r & 3) + 8 * (r >> 2) + 4 * hi;
      op[qd * 64 + l31] = oacc0[r];
      op[qd * 64 + 32 + l31] = oacc1[r];
    }
    if (hi == 0) {
      mlbuf[qg * 64 + l31] = m_run;
      mlbuf[qg * 64 + 32 + l31] = l_run;
    }
  }
  __syncthreads();
  if (half == 0) {
    float mb = mlbuf[qg * 64 + l31];
    float lb2 = mlbuf[qg * 64 + 32 + l31];
    float mmax = fmaxf(m_run, mb);
    float sa = exp2f_fast(m_run - mmax);
    float sb = exp2f_fast(mb - mmax);
    float dI = 1.0f / (l_run * sa + lb2 * sb);
    float fA = sa * dI, fB = sb * dI;
    const float* op = Opart + qg * 2048;
#pragma unroll
    for (int r = 0; r < 16; ++r) {
      int qd = (r & 3) + 8 * (r >> 2) + 4 * hi;
      float fa = __shfl(fA, qd), fb = __shfl(fB, qd);
      float o0 = oacc0[r] * fa + op[qd * 64 + l31] * fb;
      float o1 = oacc1[r] * fa + op[qd * 64 + 32 + l31] * fb;
      size_t row = (size_t)(b * 2048 + q0 + qd) * 512 + h * 64;
      O[row + l31] = f2bf(o0);
      O[row + 32 + l31] = f2bf(o1);
    }
  }
}

extern "C" void kernel_launch(void* const* d_in, const int* in_sizes, int n_in,
                              void* d_out, int out_size, void* d_ws, size_t ws_size,
                              hipStream_t stream) {
  const float* x = (const float*)d_in[0];
  const float* w_qkv = (const float*)d_in[1];
  const float* w_out = (const float*)d_in[2];
  const float* b_out = (const float*)d_in[3];
  float* out = (float*)d_out;
  char* ws = (char*)d_ws;

  unsigned short* xb    = (unsigned short*)(ws + 0);         //  8 MB [8192][512]
  unsigned short* wqkvT = (unsigned short*)(ws + 8388608);   //  1.5 MB [1536][512]
  unsigned short* woutT = (unsigned short*)(ws + 9961472);   //  0.5 MB [512][512]
  unsigned short* qkvb  = (unsigned short*)(ws + 10485760);  // 24 MB [8192][1536]
  unsigned short* vtb   = (unsigned short*)(ws + 35651584);  //  8 MB [32][64][2048]
  unsigned short* Ob    = (unsigned short*)(ws + 44040192);  //  8 MB [8192][512]

  k_convert<<<2048, 256, 0, stream>>>(x, xb);
  k_transpose_f32_bf16<<<dim3(24, 8), 256, 0, stream>>>(w_qkv, wqkvT, 512, 1536);
  k_transpose_f32_bf16<<<dim3(8, 8), 256, 0, stream>>>(w_out, woutT, 512, 512);
  k_gemm_bt<false><<<dim3(12, 64), 256, 0, stream>>>(xb, wqkvT, (void*)qkvb, nullptr,
                                                     8192, 1536, 512);
  k_build_vt<<<dim3(32, 32), 256, 0, stream>>>(qkvb, vtb);
  k_attn4<<<dim3(16, 32), 512, 0, stream>>>(qkvb, vtb, Ob);
  k_gemm_bt<true><<<dim3(4, 64), 256, 0, stream>>>(Ob, woutT, (void*)out, b_out,
                                                   8192, 512, 512);
}

// Round 10
// 175.365 us; speedup vs baseline: 1.0535x; 1.0376x over previous
//
#include <hip/hip_runtime.h>

typedef __attribute__((ext_vector_type(4))) float f32x4;
typedef __attribute__((ext_vector_type(16))) float f32x16;
typedef __attribute__((ext_vector_type(8))) short short8;

#define DEV static __device__ __forceinline__

DEV unsigned short f2bf(float f) {
  union { float f; unsigned u; } x; x.f = f;
  unsigned r = x.u + 0x7fffu + ((x.u >> 16) & 1u);
  return (unsigned short)(r >> 16);
}

DEV float bf2f(unsigned short u) {
  union { unsigned u; float f; } x; x.u = ((unsigned)u) << 16;
  return x.f;
}

DEV f32x4 mfma16(short8 a, short8 b, f32x4 c) {
  return __builtin_amdgcn_mfma_f32_16x16x32_bf16(a, b, c, 0, 0, 0);
}

DEV f32x16 mfma32(short8 a, short8 b, f32x16 c) {
  return __builtin_amdgcn_mfma_f32_32x32x16_bf16(a, b, c, 0, 0, 0);
}

DEV void gload16(const void* g, void* l) {
  __builtin_amdgcn_global_load_lds(
      (const __attribute__((address_space(1))) void*)g,
      (__attribute__((address_space(3))) void*)l, 16, 0, 0);
}

DEV float exp2f_fast(float x) {
  float r;
  asm("v_exp_f32 %0, %1" : "=v"(r) : "v"(x));
  return r;
}

DEV unsigned cvtpk(float lo, float hi) {
  unsigned r;
  asm("v_cvt_pk_bf16_f32 %0, %1, %2" : "=v"(r) : "v"(lo), "v"(hi));
  return r;
}

DEV short8 mk8(unsigned w0, unsigned w1, unsigned w2, unsigned w3) {
  union { unsigned u[4]; short8 s; } x;
  x.u[0] = w0; x.u[1] = w1; x.u[2] = w2; x.u[3] = w3;
  return x.s;
}

// two-level LDS swizzle: conflict-free for both consecutive-8 and stride-8
// b128 lane phase groupings (r9 counters: 2^22 conflicts == 4-way on every
// frag read under stride-8 grouping with the old (row&7)-only XOR).
DEV int swzrow(int r) { return (((r & 7) ^ ((r >> 3) & 7)) << 3); }

// ---------------- fused prep: x->bf16, both weight transposes ----------------
// blocks [0,2048): convert x; [2048,2240): transpose w_qkv; [2240,2304): w_out
__global__ __launch_bounds__(256) void k_prep(
    const float* __restrict__ x, unsigned short* __restrict__ xb,
    const float* __restrict__ wq, unsigned short* __restrict__ wqT,
    const float* __restrict__ wo, unsigned short* __restrict__ woT) {
  __shared__ unsigned short T[64 * 72];
  const int blk = blockIdx.x;
  const int t = threadIdx.x;
  if (blk < 2048) {
    size_t i = (size_t)blk * 256 + t;
    const f32x4* p = (const f32x4*)(x + i * 8);
    f32x4 a = p[0], b = p[1];
    short8 r;
    r[0] = f2bf(a[0]); r[1] = f2bf(a[1]); r[2] = f2bf(a[2]); r[3] = f2bf(a[3]);
    r[4] = f2bf(b[0]); r[5] = f2bf(b[1]); r[6] = f2bf(b[2]); r[7] = f2bf(b[3]);
    *(short8*)(xb + i * 8) = r;
    return;
  }
  const float* in;
  unsigned short* out;
  int C, bx, by;
  const int R = 512;
  if (blk < 2240) {
    in = wq; out = wqT; C = 1536;
    int bb = blk - 2048; bx = bb % 24; by = bb / 24;
  } else {
    in = wo; out = woT; C = 512;
    int bb = blk - 2240; bx = bb & 7; by = bb >> 3;
  }
  int r0 = by * 64, c0 = bx * 64;
  int rr = t >> 2, seg = t & 3;
  const float* p = in + (size_t)(r0 + rr) * C + c0 + seg * 16;
#pragma unroll
  for (int q = 0; q < 4; ++q) {
    f32x4 v = *(const f32x4*)(p + q * 4);
#pragma unroll
    for (int e = 0; e < 4; ++e) T[rr * 72 + seg * 16 + q * 4 + e] = f2bf(v[e]);
  }
  __syncthreads();
  short8 o0, o1;
#pragma unroll
  for (int e = 0; e < 8; ++e) o0[e] = (short)T[(seg * 16 + e) * 72 + rr];
#pragma unroll
  for (int e = 0; e < 8; ++e) o1[e] = (short)T[(seg * 16 + 8 + e) * 72 + rr];
  unsigned short* q2 = out + (size_t)(c0 + rr) * R + r0 + seg * 16;
  *(short8*)q2 = o0;
  *(short8*)(q2 + 8) = o1;
}

// ---------------- build V^T [B*H][64][2048] from qkv ----------------
__global__ __launch_bounds__(256) void k_build_vt(const unsigned short* __restrict__ qkv,
                                                  unsigned short* __restrict__ vt) {
  __shared__ unsigned short T[64 * 72];
  int n0 = blockIdx.x * 64;
  int bh = blockIdx.y;
  int b = bh >> 3, h = bh & 7;
  int t = threadIdx.x;
  int rr = t >> 2, seg = t & 3;
  const unsigned short* p =
      qkv + (size_t)(b * 2048 + n0 + rr) * 1536 + 1024 + h * 64 + seg * 16;
  *(short8*)&T[rr * 72 + seg * 16] = *(const short8*)p;
  *(short8*)&T[rr * 72 + seg * 16 + 8] = *(const short8*)(p + 8);
  __syncthreads();
  short8 o0, o1;
#pragma unroll
  for (int e = 0; e < 8; ++e) o0[e] = (short)T[(seg * 16 + e) * 72 + rr];
#pragma unroll
  for (int e = 0; e < 8; ++e) o1[e] = (short)T[(seg * 16 + 8 + e) * 72 + rr];
  unsigned short* q2 = vt + (size_t)(bh * 64 + rr) * 2048 + n0 + seg * 16;
  *(short8*)q2 = o0;
  *(short8*)(q2 + 8) = o1;
}

// ---------------- GEMM: C[M][N] = A[M][K] * Bt[N][K]^T (+bias) ----------------
// XCD-aware bijective block swizzle (nwg % 8 == 0 for both call sites).
template <bool F32OUT>
__global__ __launch_bounds__(256) void k_gemm_bt(
    const unsigned short* __restrict__ A, const unsigned short* __restrict__ Bt,
    void* __restrict__ Cp, const float* __restrict__ bias, int M, int N, int K) {
  __shared__ unsigned short Asm[128 * 64];
  __shared__ unsigned short Bsm[128 * 64];
  const int tid = threadIdx.x;
  const int lane = tid & 63, w = tid >> 6;
  const int wr = w >> 1, wc = w & 1;
  const int nbx = gridDim.x;
  const int cpx = (nbx * gridDim.y) >> 3;
  const int lin = blockIdx.y * nbx + blockIdx.x;
  const int swz = (lin & 7) * cpx + (lin >> 3);
  const int bm = (swz / nbx) * 128, bn = (swz % nbx) * 128;
  const int l15 = lane & 15, l4 = lane >> 4;
  f32x4 acc[4][4] = {};
  for (int k0 = 0; k0 < K; k0 += 64) {
    __syncthreads();
#pragma unroll
    for (int j = 0; j < 4; ++j) {
      int c = j * 256 + tid;
      gload16(A + (size_t)(bm + (c >> 3)) * K + k0 + ((c & 7) << 3),
              Asm + (size_t)(j * 256 + w * 64) * 8);
    }
#pragma unroll
    for (int j = 0; j < 4; ++j) {
      int c = j * 256 + tid;
      gload16(Bt + (size_t)(bn + (c >> 3)) * K + k0 + ((c & 7) << 3),
              Bsm + (size_t)(j * 256 + w * 64) * 8);
    }
    __syncthreads();
#pragma unroll
    for (int kc = 0; kc < 2; ++kc) {
      short8 av[4], bv[4];
#pragma unroll
      for (int i = 0; i < 4; ++i)
        av[i] = *(const short8*)&Asm[(wr * 64 + i * 16 + l15) * 64 + kc * 32 + l4 * 8];
#pragma unroll
      for (int j = 0; j < 4; ++j)
        bv[j] = *(const short8*)&Bsm[(wc * 64 + j * 16 + l15) * 64 + kc * 32 + l4 * 8];
#pragma unroll
      for (int i = 0; i < 4; ++i)
#pragma unroll
        for (int j = 0; j < 4; ++j)
          acc[i][j] = mfma16(av[i], bv[j], acc[i][j]);
    }
  }
#pragma unroll
  for (int i = 0; i < 4; ++i) {
#pragma unroll
    for (int j = 0; j < 4; ++j) {
      int col = bn + wc * 64 + j * 16 + l15;
      float bb = 0.f;
      if constexpr (F32OUT) bb = bias[col];
#pragma unroll
      for (int v = 0; v < 4; ++v) {
        int row = bm + wr * 64 + i * 16 + l4 * 4 + v;
        if constexpr (F32OUT) {
          ((float*)Cp)[(size_t)row * N + col] = acc[i][j][v] + bb;
        } else {
          ((unsigned short*)Cp)[(size_t)row * N + col] = f2bf(acc[i][j][v]);
        }
      }
    }
  }
}

// ---------------- flash attention, KV-half-split, two-level swizzle ----------
// grid (N/128, B*H), 512 threads. Wave w: qgroup = w&3 (32 q-rows), half = w>>2
// (kv rows half*32..+32 of each 64-tile). Identical to r9's k_attn4 except the
// LDS swizzle is swzrow() on both staging writes and fragment reads.
__global__ __launch_bounds__(512, 4) void k_attn5(const unsigned short* __restrict__ qkv,
                                                  const unsigned short* __restrict__ vtg,
                                                  unsigned short* __restrict__ O) {
  __shared__ unsigned short smem[16896];  // 33 KB: Ks[2][4096] | Vs[2][4096] | +1KB ml
  unsigned short* Ks0 = smem;
  unsigned short* Ks1 = smem + 4096;
  unsigned short* Vs0 = smem + 8192;
  unsigned short* Vs1 = smem + 12288;
  const int tid = threadIdx.x;
  const int lane = tid & 63, w = tid >> 6;
  const int qg = w & 3, half = w >> 2;
  const int l31 = lane & 31, hi = lane >> 5;
  const int bh = blockIdx.y, b = bh >> 3, h = bh & 7;
  const int q0 = blockIdx.x * 128 + qg * 32;
  const float CL = 0.044194173824159216f * 1.4426950408889634f;  // SCALE*log2(e)

  // Q load, fold SCALE*log2e into bf16 Q
  short8 qf[4];
  {
    const unsigned short* qp = qkv + (size_t)(b * 2048 + q0 + l31) * 1536 + h * 64;
#pragma unroll
    for (int ks = 0; ks < 4; ++ks) {
      short8 raw = *(const short8*)(qp + ks * 16 + hi * 8);
      short8 f;
#pragma unroll
      for (int e = 0; e < 8; ++e)
        f[e] = (short)f2bf(bf2f((unsigned short)raw[e]) * CL);
      qf[ks] = f;
    }
  }

  // staging: 512 threads cover 64 rows x 64 cols (16B each) for K and V
  const int sr = tid >> 3, seg = tid & 7;
  const unsigned short* kg = qkv + (size_t)b * 2048 * 1536 + 512 + h * 64 + seg * 8;
  const unsigned short* vg = vtg + (size_t)bh * 64 * 2048 + seg * 8;
  const int so = sr * 64 + ((seg * 8) ^ swzrow(sr));

  // prologue: stage tile 0
  *(short8*)&Ks0[so] = *(const short8*)(kg + (size_t)sr * 1536);
  *(short8*)&Vs0[so] = *(const short8*)(vg + (size_t)sr * 2048);
  __syncthreads();

  const int kxor = swzrow(half * 32 + l31);   // this wave's K-row swizzle
  const int v0xor = swzrow(l31);              // V rows l31 / 32+l31
  const int v1xor = swzrow(32 + l31);
  const int krow = (half * 32 + l31) * 64;

  f32x16 oacc0 = {}, oacc1 = {};
  float m_run = 0.f, l_run = 0.f;
  unsigned short* kcur = Ks0; unsigned short* knxt = Ks1;
  unsigned short* vcur = Vs0; unsigned short* vnxt = Vs1;

  for (int t = 0; t < 32; ++t) {
    // reg-prefetch tile t+1 (T14)
    short8 pk, pv;
    if (t < 31) {
      int kv = (t + 1) * 64;
      pk = *(const short8*)(kg + (size_t)(kv + sr) * 1536);
      pv = *(const short8*)(vg + (size_t)sr * 2048 + kv);
    }

    // S^T = K * Q^T over this wave's 32 kv rows (K=64 in 4 steps)
    f32x16 st = {};
    __builtin_amdgcn_s_setprio(1);
#pragma unroll
    for (int ks = 0; ks < 4; ++ks) {
      int col = ks * 16 + hi * 8;
      short8 kf = *(const short8*)&kcur[krow + (col ^ kxor)];
      st = mfma32(kf, qf[ks], st);
    }
    __builtin_amdgcn_s_setprio(0);

    // ---- online softmax (lane-local rows, q = l31) ----
    float tm[8];
#pragma unroll
    for (int r = 0; r < 8; ++r) tm[r] = fmaxf(st[r], st[r + 8]);
    float pm = fmaxf(fmaxf(fmaxf(tm[0], tm[1]), fmaxf(tm[2], tm[3])),
                     fmaxf(fmaxf(tm[4], tm[5]), fmaxf(tm[6], tm[7])));
    pm = fmaxf(pm, __shfl_xor(pm, 32));

    if (!__all(pm <= m_run + 11.5f)) {  // defer-max (rare)
      float mn = fmaxf(m_run, pm);
      float al = exp2f_fast(m_run - mn);
#pragma unroll
      for (int r = 0; r < 16; ++r) {
        int qd = (r & 3) + 8 * (r >> 2) + 4 * hi;
        float a = __shfl(al, qd);
        oacc0[r] *= a;
        oacc1[r] *= a;
      }
      l_run *= al;
      m_run = mn;
    }

    float p[16];
    float la = 0.f, lb = 0.f;
#pragma unroll
    for (int r = 0; r < 8; ++r) { p[r] = exp2f_fast(st[r] - m_run); la += p[r]; }
#pragma unroll
    for (int r = 8; r < 16; ++r) { p[r] = exp2f_fast(st[r] - m_run); lb += p[r]; }
    float lsum = la + lb;
    short8 pa[2];
#pragma unroll
    for (int g = 0; g < 2; ++g) {
      unsigned pkA0 = cvtpk(p[8 * g + 0], p[8 * g + 1]);
      unsigned pkA1 = cvtpk(p[8 * g + 2], p[8 * g + 3]);
      unsigned pkB0 = cvtpk(p[8 * g + 4], p[8 * g + 5]);
      unsigned pkB1 = cvtpk(p[8 * g + 6], p[8 * g + 7]);
      unsigned tA0 = __shfl_xor(pkA0, 32), tA1 = __shfl_xor(pkA1, 32);
      unsigned tB0 = __shfl_xor(pkB0, 32), tB1 = __shfl_xor(pkB1, 32);
      unsigned w0 = hi ? tB0 : pkA0;
      unsigned w1 = hi ? tB1 : pkA1;
      unsigned w2 = hi ? pkB0 : tA0;
      unsigned w3 = hi ? pkB1 : tA1;
      pa[g] = mk8(w0, w1, w2, w3);
    }
    lsum += __shfl_xor(lsum, 32);
    l_run += lsum;

    // ---- O += P V over this wave's kv half ----
    __builtin_amdgcn_s_setprio(1);
#pragma unroll
    for (int ks = 0; ks < 2; ++ks) {
      int col = (half * 2 + ks) * 16 + hi * 8;
      short8 vf0 = *(const short8*)&vcur[l31 * 64 + (col ^ v0xor)];
      short8 vf1 = *(const short8*)&vcur[(32 + l31) * 64 + (col ^ v1xor)];
      oacc0 = mfma32(pa[ks], vf0, oacc0);
      oacc1 = mfma32(pa[ks], vf1, oacc1);
    }
    __builtin_amdgcn_s_setprio(0);

    // write prefetched tile into the other buffer, single barrier per tile
    if (t < 31) {
      *(short8*)&knxt[so] = pk;
      *(short8*)&vnxt[so] = pv;
    }
    __syncthreads();
    { unsigned short* tp = kcur; kcur = knxt; knxt = tp; }
    { unsigned short* tp = vcur; vcur = vnxt; vnxt = tp; }
  }

  // ---- pair combine: half 1 publishes partials, half 0 merges + writes ----
  float* Opart = (float*)smem;            // [4][32][64] fp32, aliases dead Ks/Vs
  float* mlbuf = (float*)(smem + 16384);  // [4][64]: m then l per q
  if (half == 1) {
    float* op = Opart + qg * 2048;
#pragma unroll
    for (int r = 0; r < 16; ++r) {
      int qd = (r & 3) + 8 * (r >> 2) + 4 * hi;
      op[qd * 64 + l31] = oacc0[r];
      op[qd * 64 + 32 + l31] = oacc1[r];
    }
    if (hi == 0) {
      mlbuf[qg * 64 + l31] = m_run;
      mlbuf[qg * 64 + 32 + l31] = l_run;
    }
  }
  __syncthreads();
  if (half == 0) {
    float mb = mlbuf[qg * 64 + l31];
    float lb2 = mlbuf[qg * 64 + 32 + l31];
    float mmax = fmaxf(m_run, mb);
    float sa = exp2f_fast(m_run - mmax);
    float sb = exp2f_fast(mb - mmax);
    float dI = 1.0f / (l_run * sa + lb2 * sb);
    float fA = sa * dI, fB = sb * dI;
    const float* op = Opart + qg * 2048;
#pragma unroll
    for (int r = 0; r < 16; ++r) {
      int qd = (r & 3) + 8 * (r >> 2) + 4 * hi;
      float fa = __shfl(fA, qd), fb = __shfl(fB, qd);
      float o0 = oacc0[r] * fa + op[qd * 64 + l31] * fb;
      float o1 = oacc1[r] * fa + op[qd * 64 + 32 + l31] * fb;
      size_t row = (size_t)(b * 2048 + q0 + qd) * 512 + h * 64;
      O[row + l31] = f2bf(o0);
      O[row + 32 + l31] = f2bf(o1);
    }
  }
}

extern "C" void kernel_launch(void* const* d_in, const int* in_sizes, int n_in,
                              void* d_out, int out_size, void* d_ws, size_t ws_size,
                              hipStream_t stream) {
  const float* x = (const float*)d_in[0];
  const float* w_qkv = (const float*)d_in[1];
  const float* w_out = (const float*)d_in[2];
  const float* b_out = (const float*)d_in[3];
  float* out = (float*)d_out;
  char* ws = (char*)d_ws;

  unsigned short* xb    = (unsigned short*)(ws + 0);         //  8 MB [8192][512]
  unsigned short* wqkvT = (unsigned short*)(ws + 8388608);   //  1.5 MB [1536][512]
  unsigned short* woutT = (unsigned short*)(ws + 9961472);   //  0.5 MB [512][512]
  unsigned short* qkvb  = (unsigned short*)(ws + 10485760);  // 24 MB [8192][1536]
  unsigned short* vtb   = (unsigned short*)(ws + 35651584);  //  8 MB [32][64][2048]
  unsigned short* Ob    = (unsigned short*)(ws + 44040192);  //  8 MB [8192][512]

  k_prep<<<2304, 256, 0, stream>>>(x, xb, w_qkv, wqkvT, w_out, woutT);
  k_gemm_bt<false><<<dim3(12, 64), 256, 0, stream>>>(xb, wqkvT, (void*)qkvb, nullptr,
                                                     8192, 1536, 512);
  k_build_vt<<<dim3(32, 32), 256, 0, stream>>>(qkvb, vtb);
  k_attn5<<<dim3(16, 32), 512, 0, stream>>>(qkvb, vtb, Ob);
  k_gemm_bt<true><<<dim3(4, 64), 256, 0, stream>>>(Ob, woutT, (void*)out, b_out,
                                                   8192, 512, 512);
}

// Round 11
// 173.390 us; speedup vs baseline: 1.0655x; 1.0114x over previous
//
#include <hip/hip_runtime.h>

typedef __attribute__((ext_vector_type(4))) float f32x4;
typedef __attribute__((ext_vector_type(16))) float f32x16;
typedef __attribute__((ext_vector_type(8))) short short8;

#define DEV static __device__ __forceinline__

DEV unsigned short f2bf(float f) {
  union { float f; unsigned u; } x; x.f = f;
  unsigned r = x.u + 0x7fffu + ((x.u >> 16) & 1u);
  return (unsigned short)(r >> 16);
}

DEV float bf2f(unsigned short u) {
  union { unsigned u; float f; } x; x.u = ((unsigned)u) << 16;
  return x.f;
}

DEV f32x4 mfma16(short8 a, short8 b, f32x4 c) {
  return __builtin_amdgcn_mfma_f32_16x16x32_bf16(a, b, c, 0, 0, 0);
}

DEV f32x16 mfma32(short8 a, short8 b, f32x16 c) {
  return __builtin_amdgcn_mfma_f32_32x32x16_bf16(a, b, c, 0, 0, 0);
}

DEV void gload16(const void* g, void* l) {
  __builtin_amdgcn_global_load_lds(
      (const __attribute__((address_space(1))) void*)g,
      (__attribute__((address_space(3))) void*)l, 16, 0, 0);
}

DEV float exp2f_fast(float x) {
  float r;
  asm("v_exp_f32 %0, %1" : "=v"(r) : "v"(x));
  return r;
}

DEV unsigned cvtpk(float lo, float hi) {
  unsigned r;
  asm("v_cvt_pk_bf16_f32 %0, %1, %2" : "=v"(r) : "v"(lo), "v"(hi));
  return r;
}

DEV short8 mk8(unsigned w0, unsigned w1, unsigned w2, unsigned w3) {
  union { unsigned u[4]; short8 s; } x;
  x.u[0] = w0; x.u[1] = w1; x.u[2] = w2; x.u[3] = w3;
  return x.s;
}

// two-level LDS swizzle (r10: verified BANK_CONFLICT 4.2M -> 0)
DEV int swzrow(int r) { return (((r & 7) ^ ((r >> 3) & 7)) << 3); }

// ---------------- fused prep: x->bf16, both weight transposes ----------------
__global__ __launch_bounds__(256) void k_prep(
    const float* __restrict__ x, unsigned short* __restrict__ xb,
    const float* __restrict__ wq, unsigned short* __restrict__ wqT,
    const float* __restrict__ wo, unsigned short* __restrict__ woT) {
  __shared__ unsigned short T[64 * 72];
  const int blk = blockIdx.x;
  const int t = threadIdx.x;
  if (blk < 2048) {
    size_t i = (size_t)blk * 256 + t;
    const f32x4* p = (const f32x4*)(x + i * 8);
    f32x4 a = p[0], b = p[1];
    short8 r;
    r[0] = f2bf(a[0]); r[1] = f2bf(a[1]); r[2] = f2bf(a[2]); r[3] = f2bf(a[3]);
    r[4] = f2bf(b[0]); r[5] = f2bf(b[1]); r[6] = f2bf(b[2]); r[7] = f2bf(b[3]);
    *(short8*)(xb + i * 8) = r;
    return;
  }
  const float* in;
  unsigned short* out;
  int C, bx, by;
  const int R = 512;
  if (blk < 2240) {
    in = wq; out = wqT; C = 1536;
    int bb = blk - 2048; bx = bb % 24; by = bb / 24;
  } else {
    in = wo; out = woT; C = 512;
    int bb = blk - 2240; bx = bb & 7; by = bb >> 3;
  }
  int r0 = by * 64, c0 = bx * 64;
  int rr = t >> 2, seg = t & 3;
  const float* p = in + (size_t)(r0 + rr) * C + c0 + seg * 16;
#pragma unroll
  for (int q = 0; q < 4; ++q) {
    f32x4 v = *(const f32x4*)(p + q * 4);
#pragma unroll
    for (int e = 0; e < 4; ++e) T[rr * 72 + seg * 16 + q * 4 + e] = f2bf(v[e]);
  }
  __syncthreads();
  short8 o0, o1;
#pragma unroll
  for (int e = 0; e < 8; ++e) o0[e] = (short)T[(seg * 16 + e) * 72 + rr];
#pragma unroll
  for (int e = 0; e < 8; ++e) o1[e] = (short)T[(seg * 16 + 8 + e) * 72 + rr];
  unsigned short* q2 = out + (size_t)(c0 + rr) * R + r0 + seg * 16;
  *(short8*)q2 = o0;
  *(short8*)(q2 + 8) = o1;
}

// ---------------- GEMM: C[M][N] = A[M][K] * Bt[N][K]^T (+bias) ----------------
// NT: N-tile (128 or 64). WVT: V-column blocks (bn>=1024) write transposed
// vt[(b*8+h)*64+hd][npos] via an LDS re-tile instead of qkvb (attn never reads
// qkvb's V third). XCD-aware bijective block swizzle (nwg % 8 == 0).
template <bool F32OUT, int NT, bool WVT>
__global__ __launch_bounds__(256) void k_gemm_bt(
    const unsigned short* __restrict__ A, const unsigned short* __restrict__ Bt,
    void* __restrict__ Cp, const float* __restrict__ bias,
    unsigned short* __restrict__ vt, int M, int N, int K) {
  constexpr int NJ = NT / 32;           // j-frags per wave
  constexpr int SHSZ = WVT ? (128 * 136) : (8192 + NT * 64);
  __shared__ unsigned short SH[SHSZ];
  unsigned short* Asm = SH;
  unsigned short* Bsm = SH + 8192;
  const int tid = threadIdx.x;
  const int lane = tid & 63, w = tid >> 6;
  const int wr = w >> 1, wc = w & 1;
  const int nbx = gridDim.x;
  const int cpx = (nbx * gridDim.y) >> 3;
  const int lin = blockIdx.y * nbx + blockIdx.x;
  const int swz = (lin & 7) * cpx + (lin >> 3);
  const int bm = (swz / nbx) * 128, bn = (swz % nbx) * NT;
  const int l15 = lane & 15, l4 = lane >> 4;
  f32x4 acc[4][NJ] = {};
  for (int k0 = 0; k0 < K; k0 += 64) {
    __syncthreads();
#pragma unroll
    for (int j = 0; j < 4; ++j) {
      int c = j * 256 + tid;
      gload16(A + (size_t)(bm + (c >> 3)) * K + k0 + ((c & 7) << 3),
              Asm + (size_t)(j * 256 + w * 64) * 8);
    }
#pragma unroll
    for (int j = 0; j < NJ; ++j) {
      int c = j * 256 + tid;
      gload16(Bt + (size_t)(bn + (c >> 3)) * K + k0 + ((c & 7) << 3),
              Bsm + (size_t)(j * 256 + w * 64) * 8);
    }
    __syncthreads();
#pragma unroll
    for (int kc = 0; kc < 2; ++kc) {
      short8 av[4], bv[NJ];
#pragma unroll
      for (int i = 0; i < 4; ++i)
        av[i] = *(const short8*)&Asm[(wr * 64 + i * 16 + l15) * 64 + kc * 32 + l4 * 8];
#pragma unroll
      for (int j = 0; j < NJ; ++j)
        bv[j] = *(const short8*)&Bsm[(wc * (NT / 2) + j * 16 + l15) * 64 + kc * 32 + l4 * 8];
#pragma unroll
      for (int i = 0; i < 4; ++i)
#pragma unroll
        for (int j = 0; j < NJ; ++j)
          acc[i][j] = mfma16(av[i], bv[j], acc[i][j]);
    }
  }
  if (WVT && bn >= 1024) {
    // V columns: transpose 128x128 acc tile through LDS, emit vt rows.
    __syncthreads();  // Asm/Bsm reads done; SH reused as T[128 col][136 row]
#pragma unroll
    for (int i = 0; i < 4; ++i)
#pragma unroll
      for (int j = 0; j < NJ; ++j) {
        int colL = wc * (NT / 2) + j * 16 + l15;
#pragma unroll
        for (int v = 0; v < 4; ++v)
          SH[colL * 136 + wr * 64 + i * 16 + l4 * 4 + v] = f2bf(acc[i][j][v]);
      }
    __syncthreads();
    const int vtrow = tid >> 1, half2 = tid & 1;   // vtrow: 2 heads x 64 hd
    const int b2 = bm >> 11, npos0 = bm & 2047;
    const int h = ((bn - 1024) >> 6) + (vtrow >> 6);
    const int hd = vtrow & 63;
    unsigned short* dst =
        vt + ((size_t)(b2 * 8 + h) * 64 + hd) * 2048 + npos0 + half2 * 64;
    const unsigned short* srcT = SH + vtrow * 136 + half2 * 64;
#pragma unroll
    for (int e = 0; e < 8; ++e)
      *(short8*)(dst + e * 8) = *(const short8*)(srcT + e * 8);
    return;
  }
#pragma unroll
  for (int i = 0; i < 4; ++i) {
#pragma unroll
    for (int j = 0; j < NJ; ++j) {
      int col = bn + wc * (NT / 2) + j * 16 + l15;
      float bb = 0.f;
      if constexpr (F32OUT) bb = bias[col];
#pragma unroll
      for (int v = 0; v < 4; ++v) {
        int row = bm + wr * 64 + i * 16 + l4 * 4 + v;
        if constexpr (F32OUT) {
          ((float*)Cp)[(size_t)row * N + col] = acc[i][j][v] + bb;
        } else {
          ((unsigned short*)Cp)[(size_t)row * N + col] = f2bf(acc[i][j][v]);
        }
      }
    }
  }
}

// ---------------- flash attention, KV-half-split, two-level swizzle ----------
// (r10-verified: 0 bank conflicts; frozen this round)
__global__ __launch_bounds__(512, 4) void k_attn5(const unsigned short* __restrict__ qkv,
                                                  const unsigned short* __restrict__ vtg,
                                                  unsigned short* __restrict__ O) {
  __shared__ unsigned short smem[16896];
  unsigned short* Ks0 = smem;
  unsigned short* Ks1 = smem + 4096;
  unsigned short* Vs0 = smem + 8192;
  unsigned short* Vs1 = smem + 12288;
  const int tid = threadIdx.x;
  const int lane = tid & 63, w = tid >> 6;
  const int qg = w & 3, half = w >> 2;
  const int l31 = lane & 31, hi = lane >> 5;
  const int bh = blockIdx.y, b = bh >> 3, h = bh & 7;
  const int q0 = blockIdx.x * 128 + qg * 32;
  const float CL = 0.044194173824159216f * 1.4426950408889634f;  // SCALE*log2(e)

  short8 qf[4];
  {
    const unsigned short* qp = qkv + (size_t)(b * 2048 + q0 + l31) * 1536 + h * 64;
#pragma unroll
    for (int ks = 0; ks < 4; ++ks) {
      short8 raw = *(const short8*)(qp + ks * 16 + hi * 8);
      short8 f;
#pragma unroll
      for (int e = 0; e < 8; ++e)
        f[e] = (short)f2bf(bf2f((unsigned short)raw[e]) * CL);
      qf[ks] = f;
    }
  }

  const int sr = tid >> 3, seg = tid & 7;
  const unsigned short* kg = qkv + (size_t)b * 2048 * 1536 + 512 + h * 64 + seg * 8;
  const unsigned short* vg = vtg + (size_t)bh * 64 * 2048 + seg * 8;
  const int so = sr * 64 + ((seg * 8) ^ swzrow(sr));

  *(short8*)&Ks0[so] = *(const short8*)(kg + (size_t)sr * 1536);
  *(short8*)&Vs0[so] = *(const short8*)(vg + (size_t)sr * 2048);
  __syncthreads();

  const int kxor = swzrow(half * 32 + l31);
  const int v0xor = swzrow(l31);
  const int v1xor = swzrow(32 + l31);
  const int krow = (half * 32 + l31) * 64;

  f32x16 oacc0 = {}, oacc1 = {};
  float m_run = 0.f, l_run = 0.f;
  unsigned short* kcur = Ks0; unsigned short* knxt = Ks1;
  unsigned short* vcur = Vs0; unsigned short* vnxt = Vs1;

  for (int t = 0; t < 32; ++t) {
    short8 pk, pv;
    if (t < 31) {
      int kv = (t + 1) * 64;
      pk = *(const short8*)(kg + (size_t)(kv + sr) * 1536);
      pv = *(const short8*)(vg + (size_t)sr * 2048 + kv);
    }

    f32x16 st = {};
    __builtin_amdgcn_s_setprio(1);
#pragma unroll
    for (int ks = 0; ks < 4; ++ks) {
      int col = ks * 16 + hi * 8;
      short8 kf = *(const short8*)&kcur[krow + (col ^ kxor)];
      st = mfma32(kf, qf[ks], st);
    }
    __builtin_amdgcn_s_setprio(0);

    float tm[8];
#pragma unroll
    for (int r = 0; r < 8; ++r) tm[r] = fmaxf(st[r], st[r + 8]);
    float pm = fmaxf(fmaxf(fmaxf(tm[0], tm[1]), fmaxf(tm[2], tm[3])),
                     fmaxf(fmaxf(tm[4], tm[5]), fmaxf(tm[6], tm[7])));
    pm = fmaxf(pm, __shfl_xor(pm, 32));

    if (!__all(pm <= m_run + 11.5f)) {
      float mn = fmaxf(m_run, pm);
      float al = exp2f_fast(m_run - mn);
#pragma unroll
      for (int r = 0; r < 16; ++r) {
        int qd = (r & 3) + 8 * (r >> 2) + 4 * hi;
        float a = __shfl(al, qd);
        oacc0[r] *= a;
        oacc1[r] *= a;
      }
      l_run *= al;
      m_run = mn;
    }

    float p[16];
    float la = 0.f, lb = 0.f;
#pragma unroll
    for (int r = 0; r < 8; ++r) { p[r] = exp2f_fast(st[r] - m_run); la += p[r]; }
#pragma unroll
    for (int r = 8; r < 16; ++r) { p[r] = exp2f_fast(st[r] - m_run); lb += p[r]; }
    float lsum = la + lb;
    short8 pa[2];
#pragma unroll
    for (int g = 0; g < 2; ++g) {
      unsigned pkA0 = cvtpk(p[8 * g + 0], p[8 * g + 1]);
      unsigned pkA1 = cvtpk(p[8 * g + 2], p[8 * g + 3]);
      unsigned pkB0 = cvtpk(p[8 * g + 4], p[8 * g + 5]);
      unsigned pkB1 = cvtpk(p[8 * g + 6], p[8 * g + 7]);
      unsigned tA0 = __shfl_xor(pkA0, 32), tA1 = __shfl_xor(pkA1, 32);
      unsigned tB0 = __shfl_xor(pkB0, 32), tB1 = __shfl_xor(pkB1, 32);
      unsigned w0 = hi ? tB0 : pkA0;
      unsigned w1 = hi ? tB1 : pkA1;
      unsigned w2 = hi ? pkB0 : tA0;
      unsigned w3 = hi ? pkB1 : tA1;
      pa[g] = mk8(w0, w1, w2, w3);
    }
    lsum += __shfl_xor(lsum, 32);
    l_run += lsum;

    __builtin_amdgcn_s_setprio(1);
#pragma unroll
    for (int ks = 0; ks < 2; ++ks) {
      int col = (half * 2 + ks) * 16 + hi * 8;
      short8 vf0 = *(const short8*)&vcur[l31 * 64 + (col ^ v0xor)];
      short8 vf1 = *(const short8*)&vcur[(32 + l31) * 64 + (col ^ v1xor)];
      oacc0 = mfma32(pa[ks], vf0, oacc0);
      oacc1 = mfma32(pa[ks], vf1, oacc1);
    }
    __builtin_amdgcn_s_setprio(0);

    if (t < 31) {
      *(short8*)&knxt[so] = pk;
      *(short8*)&vnxt[so] = pv;
    }
    __syncthreads();
    { unsigned short* tp = kcur; kcur = knxt; knxt = tp; }
    { unsigned short* tp = vcur; vcur = vnxt; vnxt = tp; }
  }

  float* Opart = (float*)smem;
  float* mlbuf = (float*)(smem + 16384);
  if (half == 1) {
    float* op = Opart + qg * 2048;
#pragma unroll
    for (int r = 0; r < 16; ++r) {
      int qd = (r & 3) + 8 * (r >> 2) + 4 * hi;
      op[qd * 64 + l31] = oacc0[r];
      op[qd * 64 + 32 + l31] = oacc1[r];
    }
    if (hi == 0) {
      mlbuf[qg * 64 + l31] = m_run;
      mlbuf[qg * 64 + 32 + l31] = l_run;
    }
  }
  __syncthreads();
  if (half == 0) {
    float mb = mlbuf[qg * 64 + l31];
    float lb2 = mlbuf[qg * 64 + 32 + l31];
    float mmax = fmaxf(m_run, mb);
    float sa = exp2f_fast(m_run - mmax);
    float sb = exp2f_fast(mb - mmax);
    float dI = 1.0f / (l_run * sa + lb2 * sb);
    float fA = sa * dI, fB = sb * dI;
    const float* op = Opart + qg * 2048;
#pragma unroll
    for (int r = 0; r < 16; ++r) {
      int qd = (r & 3) + 8 * (r >> 2) + 4 * hi;
      float fa = __shfl(fA, qd), fb = __shfl(fB, qd);
      float o0 = oacc0[r] * fa + op[qd * 64 + l31] * fb;
      float o1 = oacc1[r] * fa + op[qd * 64 + 32 + l31] * fb;
      size_t row = (size_t)(b * 2048 + q0 + qd) * 512 + h * 64;
      O[row + l31] = f2bf(o0);
      O[row + 32 + l31] = f2bf(o1);
    }
  }
}

extern "C" void kernel_launch(void* const* d_in, const int* in_sizes, int n_in,
                              void* d_out, int out_size, void* d_ws, size_t ws_size,
                              hipStream_t stream) {
  const float* x = (const float*)d_in[0];
  const float* w_qkv = (const float*)d_in[1];
  const float* w_out = (const float*)d_in[2];
  const float* b_out = (const float*)d_in[3];
  float* out = (float*)d_out;
  char* ws = (char*)d_ws;

  unsigned short* xb    = (unsigned short*)(ws + 0);         //  8 MB [8192][512]
  unsigned short* wqkvT = (unsigned short*)(ws + 8388608);   //  1.5 MB [1536][512]
  unsigned short* woutT = (unsigned short*)(ws + 9961472);   //  0.5 MB [512][512]
  unsigned short* qkvb  = (unsigned short*)(ws + 10485760);  // 24 MB [8192][1536]
  unsigned short* vtb   = (unsigned short*)(ws + 35651584);  //  8 MB [32][64][2048]
  unsigned short* Ob    = (unsigned short*)(ws + 44040192);  //  8 MB [8192][512]

  k_prep<<<2304, 256, 0, stream>>>(x, xb, w_qkv, wqkvT, w_out, woutT);
  k_gemm_bt<false, 128, true><<<dim3(12, 64), 256, 0, stream>>>(
      xb, wqkvT, (void*)qkvb, nullptr, vtb, 8192, 1536, 512);
  k_attn5<<<dim3(16, 32), 512, 0, stream>>>(qkvb, vtb, Ob);
  k_gemm_bt<true, 64, false><<<dim3(8, 64), 256, 0, stream>>>(
      Ob, woutT, (void*)out, b_out, nullptr, 8192, 512, 512);
}